// Round 2
// baseline (512.190 us; speedup 1.0000x reference)
//
#include <hip/hip_runtime.h>
#include <hip/hip_bf16.h>

typedef __bf16 bf16x8 __attribute__((ext_vector_type(8)));
typedef float floatx4 __attribute__((ext_vector_type(4)));

#define KDIM 2048
#define MDIM 512
#define HWDIM 4096
#define BN 64
#define BK 64
#define NITER (KDIM / BK)   // 32

// Prologue: Wc[o][c] = (bf16) W[o][c][0][4].
// Coalesced float4 reads of the whole W (512*2048*9 floats = 2,359,296 float4).
// Global float index f is a center tap iff f % 9 == 4; Wc index = f/9.
__global__ void extract_w_kernel(const float* __restrict__ W, __bf16* __restrict__ Wc) {
  const int idx = blockIdx.x * 256 + threadIdx.x;
  const float4 v = ((const float4*)W)[idx];
  const float vv[4] = {v.x, v.y, v.z, v.w};
  const int f0 = idx * 4;
#pragma unroll
  for (int j = 0; j < 4; ++j) {
    const int f = f0 + j;
    if (f % 9 == 4) Wc[f / 9] = (__bf16)vv[j];
  }
}

// One block = full M(512) x 64-hw panel. 8 waves; wave w owns M rows [64w,64w+64).
// A direct from L2/L3-resident Wc. B double-buffered LDS (BK=64), staged by ALL
// 8 waves (wave w covers k rows [8w,8w+8), lane = hw), depth-2 register prefetch.
// Raw s_barrier + lgkmcnt(0)-only wait: global prefetch loads stay in flight
// across the barrier (no vmcnt(0) drain -> no per-iteration HBM-latency stall).
// Swizzle: 8 granules of 8 bf16 per 128B row; phys granule = g ^ (hw&7) ->
// uniform accesses on both ds_write_b128 and ds_read_b128.
__global__ __launch_bounds__(512, 4) void conv1x1_kernel(
    const float* __restrict__ fea, const __bf16* __restrict__ Wc,
    const float* __restrict__ bias, float* __restrict__ out) {
  __shared__ __align__(16) __bf16 Bs[2][BN * BK];   // 2 x 8 KB

  const int t    = threadIdx.x;
  const int wave = t >> 6;
  const int lane = t & 63;
  const int l15  = lane & 15;
  const int quad = lane >> 4;
  const int wm   = wave * 64;

  const int img = blockIdx.x >> 6;
  const int nb  = blockIdx.x & 63;

  const float* feaN = fea + (size_t)img * KDIM * HWDIM + (size_t)nb * BN;
  float*       outN = out + (size_t)img * MDIM * HWDIM + (size_t)nb * BN;

  // ---- B staging (all 8 waves): thread covers hw=lane, k in [8*wave, 8*wave+8) ----
  const int hw   = lane;
  const int boff = hw * BK + ((wave ^ (hw & 7)) * 8);   // swizzled elem offset
  const float* bsrc = feaN + (size_t)wave * 8 * HWDIM + hw;

  // ---- A: direct global loads from Wc ----
  const __bf16* aptr = Wc + (size_t)(wm + l15) * KDIM + quad * 8;

  float bpf[2][8];   // depth-2 B prefetch registers (8 f32/thread/tile)
  floatx4 acc[4][4];
#pragma unroll
  for (int i = 0; i < 4; ++i)
#pragma unroll
    for (int j = 0; j < 4; ++j) acc[i][j] = (floatx4){0.f, 0.f, 0.f, 0.f};

  // ---- prologue: issue B(0), B(1); convert+write B(0); barrier keeps B(1) in flight ----
#pragma unroll
  for (int j = 0; j < 8; ++j) bpf[0][j] = bsrc[(size_t)j * HWDIM];
#pragma unroll
  for (int j = 0; j < 8; ++j) bpf[1][j] = bsrc[(size_t)(BK + j) * HWDIM];
  {
    bf16x8 h0;
#pragma unroll
    for (int j = 0; j < 8; ++j) h0[j] = (__bf16)bpf[0][j];
    *(bf16x8*)&Bs[0][boff] = h0;
  }
  asm volatile("s_waitcnt lgkmcnt(0)" ::: "memory");
  __builtin_amdgcn_s_barrier();
  asm volatile("" ::: "memory");

  // Body (CUR = i&1, compile-time):
  //  1) A-frag loads issue first (oldest after prev prefetch in vmcnt FIFO)
  //  2) convert+write B(i+1): counted vmcnt wait retires ONLY prev prefetch
  //  3) issue B(i+2) prefetch (stays outstanding across the barrier)
  //  4) ds_read B frags + MFMA (counted vmcnt wait retires A frags only)
  //  5) lgkmcnt(0) + raw s_barrier (no vmcnt drain)
#define KBODY(I, CUR)                                                          \
  {                                                                            \
    const int i_ = (I);                                                        \
    bf16x8 af[2][4];                                                           \
    const __bf16* ap = aptr + (size_t)i_ * BK;                                 \
    _Pragma("unroll")                                                          \
    for (int s = 0; s < 2; ++s)                                                \
      _Pragma("unroll")                                                        \
      for (int mt = 0; mt < 4; ++mt)                                           \
        af[s][mt] = *(const bf16x8*)(ap + (size_t)(mt * 16) * KDIM + s * 32);  \
    if (i_ + 1 < NITER) {                                                      \
      bf16x8 hn;                                                               \
      _Pragma("unroll")                                                        \
      for (int j = 0; j < 8; ++j) hn[j] = (__bf16)bpf[(CUR) ^ 1][j];           \
      *(bf16x8*)&Bs[(CUR) ^ 1][boff] = hn;                                     \
    }                                                                          \
    if (i_ + 2 < NITER) {                                                      \
      const float* p = bsrc + (size_t)(i_ + 2) * BK * HWDIM;                   \
      _Pragma("unroll")                                                        \
      for (int j = 0; j < 8; ++j) bpf[(CUR)][j] = p[(size_t)j * HWDIM];        \
    }                                                                          \
    _Pragma("unroll")                                                          \
    for (int s = 0; s < 2; ++s)                                                \
      _Pragma("unroll")                                                        \
      for (int nt = 0; nt < 4; ++nt) {                                         \
        const int n_ = nt * 16 + l15;                                          \
        const bf16x8 bfr = *(const bf16x8*)&Bs[(CUR)][n_ * BK +                \
                              (((s * 4 + quad) ^ (n_ & 7)) * 8)];              \
        _Pragma("unroll")                                                      \
        for (int mt = 0; mt < 4; ++mt)                                         \
          acc[mt][nt] = __builtin_amdgcn_mfma_f32_16x16x32_bf16(af[s][mt],     \
                            bfr, acc[mt][nt], 0, 0, 0);                        \
      }                                                                        \
    if (i_ + 1 < NITER) {                                                      \
      asm volatile("s_waitcnt lgkmcnt(0)" ::: "memory");                       \
      __builtin_amdgcn_s_barrier();                                            \
      asm volatile("" ::: "memory");                                           \
    }                                                                          \
  }

  for (int i = 0; i < NITER; i += 2) {
    KBODY(i, 0)
    KBODY(i + 1, 1)
  }
#undef KBODY

  // Epilogue: bias + relu  (C/D: col = l15, row = quad*4 + r — verified earlier)
#pragma unroll
  for (int mt = 0; mt < 4; ++mt) {
    const int o0 = wm + mt * 16 + quad * 4;
    const float4 bv = *(const float4*)(bias + o0);
    const float bvr[4] = {bv.x, bv.y, bv.z, bv.w};
#pragma unroll
    for (int r = 0; r < 4; ++r) {
      const size_t ro = (size_t)(o0 + r) * HWDIM;
#pragma unroll
      for (int nt = 0; nt < 4; ++nt) {
        float x = acc[mt][nt][r] + bvr[r];
        outN[ro + nt * 16 + l15] = x > 0.f ? x : 0.f;
      }
    }
  }
}

extern "C" void kernel_launch(void* const* d_in, const int* in_sizes, int n_in,
                              void* d_out, int out_size, void* d_ws, size_t ws_size,
                              hipStream_t stream) {
  const float* fea  = (const float*)d_in[0];
  const float* W    = (const float*)d_in[1];
  const float* bias = (const float*)d_in[2];
  float* out = (float*)d_out;
  __bf16* Wc = (__bf16*)d_ws;   // 2 MB scratch

  // 512*2048*9 floats / 4 per thread / 256 per block = 9216 blocks (exact)
  hipLaunchKernelGGL(extract_w_kernel, dim3(9216), dim3(256), 0, stream, W, Wc);
  hipLaunchKernelGGL(conv1x1_kernel, dim3(512), dim3(512), 0, stream, fea, Wc, bias, out);
}

// Round 3
// 456.610 us; speedup vs baseline: 1.1217x; 1.1217x over previous
//
#include <hip/hip_runtime.h>
#include <hip/hip_bf16.h>

typedef __bf16 bf16x8 __attribute__((ext_vector_type(8)));
typedef float floatx4 __attribute__((ext_vector_type(4)));

#define KDIM 2048
#define MDIM 512
#define HWDIM 4096
#define BN 128
#define BK 64
#define NITER (KDIM / BK)   // 32

// Prologue: Wc[o][c] = (bf16) W[o][c][0][4].
// Coalesced float4 reads of all of W; float index f is a center tap iff f%9==4.
__global__ void extract_w_kernel(const float* __restrict__ W, __bf16* __restrict__ Wc) {
  const int idx = blockIdx.x * 256 + threadIdx.x;
  const float4 v = ((const float4*)W)[idx];
  const float vv[4] = {v.x, v.y, v.z, v.w};
  const int f0 = idx * 4;
#pragma unroll
  for (int j = 0; j < 4; ++j) {
    const int f = f0 + j;
    if (f % 9 == 4) Wc[f / 9] = (__bf16)vv[j];
  }
}

// 256 blocks = 8 img x 32 nb (BN=128). 1024 threads = 16 waves; wave w owns
// M rows [32w, 32w+32) x all N=128  (acc[2][8], 64 regs). One block per CU.
// A: direct global loads from Wc. Halved vs BN=64: total A traffic 512 MB.
// fea loads + out stores are NON-TEMPORAL so the streams don't evict Wc from
// the per-XCD L2 (Wc = 2 MB of 4 MB L2) -> A path served from L2, not L3.
// B: double-buffered LDS (128 hw x 64 k bf16, 2 x 16 KB), staged by all 16
// waves (thread: hw = lane+64*(wave&1), k in [8g,8g+8), g = wave>>1), with
// depth-2 register prefetch. Swizzle: 8 granules of 8 bf16 per 128 B row;
// phys granule = g ^ (hw&7): uniform 8 accesses/bank on both ds_write_b128
// and ds_read_b128 (verified 0 conflicts with this scheme in earlier rounds).
__global__ __launch_bounds__(1024, 4) void conv1x1_kernel(
    const float* __restrict__ fea, const __bf16* __restrict__ Wc,
    const float* __restrict__ bias, float* __restrict__ out) {
  __shared__ __align__(16) __bf16 Bs[2][BN * BK];   // 2 x 16 KB

  const int t    = threadIdx.x;
  const int wave = t >> 6;        // 0..15
  const int lane = t & 63;
  const int l15  = lane & 15;
  const int quad = lane >> 4;
  const int wm   = wave * 32;     // M rows [wm, wm+32)

  const int img = blockIdx.x >> 5;
  const int nb  = blockIdx.x & 31;

  const float* feaN = fea + (size_t)img * KDIM * HWDIM + (size_t)nb * BN;
  float*       outN = out + (size_t)img * MDIM * HWDIM + (size_t)nb * BN;

  // ---- B staging (all 16 waves): hw = lane+64*(wave&1), k in [8g, 8g+8) ----
  const int hw   = lane + ((wave & 1) << 6);           // 0..127
  const int g    = wave >> 1;                          // 0..7
  const int boff = hw * BK + ((g ^ (hw & 7)) * 8);     // swizzled elem offset
  const float* bsrc = feaN + (size_t)g * 8 * HWDIM + hw;

  // ---- A: direct global loads from Wc (cached; L2-resident by design) ----
  const __bf16* aptr = Wc + (size_t)(wm + l15) * KDIM + quad * 8;

  float bpf[2][8];     // depth-2 B prefetch registers
  floatx4 acc[2][8];   // mt x nt
#pragma unroll
  for (int i = 0; i < 2; ++i)
#pragma unroll
    for (int j = 0; j < 8; ++j) acc[i][j] = (floatx4){0.f, 0.f, 0.f, 0.f};

  // ---- prologue: issue B(0), B(1); convert+write B(0) ----
#pragma unroll
  for (int j = 0; j < 8; ++j)
    bpf[0][j] = __builtin_nontemporal_load(bsrc + (size_t)j * HWDIM);
#pragma unroll
  for (int j = 0; j < 8; ++j)
    bpf[1][j] = __builtin_nontemporal_load(bsrc + (size_t)(BK + j) * HWDIM);
  {
    bf16x8 h0;
#pragma unroll
    for (int j = 0; j < 8; ++j) h0[j] = (__bf16)bpf[0][j];
    *(bf16x8*)&Bs[0][boff] = h0;
  }
  __syncthreads();

  // Body (CUR = i&1, compile-time; plain __syncthreads for safety):
  //  1) A-frag loads (L2)
  //  2) convert+write B(i+1) to LDS (waits only the 1-iter-old prefetch)
  //  3) issue B(i+2) prefetch
  //  4) ds_read B frags + MFMA
  //  5) __syncthreads
#define KBODY(I, CUR)                                                          \
  {                                                                            \
    const int i_ = (I);                                                        \
    bf16x8 af[2][2];                                                           \
    const __bf16* ap = aptr + (size_t)i_ * BK;                                 \
    _Pragma("unroll")                                                          \
    for (int s = 0; s < 2; ++s)                                                \
      _Pragma("unroll")                                                        \
      for (int mt = 0; mt < 2; ++mt)                                           \
        af[s][mt] = *(const bf16x8*)(ap + (size_t)(mt * 16) * KDIM + s * 32);  \
    if (i_ + 1 < NITER) {                                                      \
      bf16x8 hn;                                                               \
      _Pragma("unroll")                                                        \
      for (int j = 0; j < 8; ++j) hn[j] = (__bf16)bpf[(CUR) ^ 1][j];           \
      *(bf16x8*)&Bs[(CUR) ^ 1][boff] = hn;                                     \
    }                                                                          \
    if (i_ + 2 < NITER) {                                                      \
      const float* p = bsrc + (size_t)(i_ + 2) * BK * HWDIM;                   \
      _Pragma("unroll")                                                        \
      for (int j = 0; j < 8; ++j)                                              \
        bpf[(CUR)][j] = __builtin_nontemporal_load(p + (size_t)j * HWDIM);     \
    }                                                                          \
    _Pragma("unroll")                                                          \
    for (int s = 0; s < 2; ++s)                                                \
      _Pragma("unroll")                                                        \
      for (int nt = 0; nt < 8; ++nt) {                                         \
        const int n_ = nt * 16 + l15;                                          \
        const bf16x8 bfr = *(const bf16x8*)&Bs[(CUR)][n_ * BK +                \
                              (((s * 4 + quad) ^ (n_ & 7)) * 8)];              \
        _Pragma("unroll")                                                      \
        for (int mt = 0; mt < 2; ++mt)                                         \
          acc[mt][nt] = __builtin_amdgcn_mfma_f32_16x16x32_bf16(af[s][mt],     \
                            bfr, acc[mt][nt], 0, 0, 0);                        \
      }                                                                        \
    __syncthreads();                                                           \
  }

  for (int i = 0; i < NITER; i += 2) {
    KBODY(i, 0)
    KBODY(i + 1, 1)
  }
#undef KBODY

  // Epilogue: bias + relu  (C/D: col = l15, row = quad*4 + r — verified)
#pragma unroll
  for (int mt = 0; mt < 2; ++mt) {
    const int o0 = wm + mt * 16 + quad * 4;
    const float4 bv = *(const float4*)(bias + o0);
    const float bvr[4] = {bv.x, bv.y, bv.z, bv.w};
#pragma unroll
    for (int r = 0; r < 4; ++r) {
      const size_t ro = (size_t)(o0 + r) * HWDIM;
#pragma unroll
      for (int nt = 0; nt < 8; ++nt) {
        float x = acc[mt][nt][r] + bvr[r];
        x = x > 0.f ? x : 0.f;
        __builtin_nontemporal_store(x, &outN[ro + nt * 16 + l15]);
      }
    }
  }
}

extern "C" void kernel_launch(void* const* d_in, const int* in_sizes, int n_in,
                              void* d_out, int out_size, void* d_ws, size_t ws_size,
                              hipStream_t stream) {
  const float* fea  = (const float*)d_in[0];
  const float* W    = (const float*)d_in[1];
  const float* bias = (const float*)d_in[2];
  float* out = (float*)d_out;
  __bf16* Wc = (__bf16*)d_ws;   // 2 MB scratch

  // 512*2048*9 floats / 4 per thread / 256 per block = 9216 blocks (exact)
  hipLaunchKernelGGL(extract_w_kernel, dim3(9216), dim3(256), 0, stream, W, Wc);
  hipLaunchKernelGGL(conv1x1_kernel, dim3(256), dim3(1024), 0, stream, fea, Wc, bias, out);
}

// Round 4
// 437.427 us; speedup vs baseline: 1.1709x; 1.0439x over previous
//
#include <hip/hip_runtime.h>
#include <hip/hip_bf16.h>

typedef __bf16 bf16x8 __attribute__((ext_vector_type(8)));
typedef float floatx4 __attribute__((ext_vector_type(4)));

#define KDIM 2048
#define MDIM 512
#define HWDIM 4096
#define BN 128
#define BM 256
#define BK 32
#define NITER (KDIM / BK)   // 64

// Prologue: Wc[o][c] = (bf16) W[o][c][0][4].
// Coalesced float4 reads of all of W; float index f is a center tap iff f%9==4.
__global__ void extract_w_kernel(const float* __restrict__ W, __bf16* __restrict__ Wc) {
  const int idx = blockIdx.x * 256 + threadIdx.x;
  const float4 v = ((const float4*)W)[idx];
  const float vv[4] = {v.x, v.y, v.z, v.w};
  const int f0 = idx * 4;
#pragma unroll
  for (int j = 0; j < 4; ++j) {
    const int f = f0 + j;
    if (f % 9 == 4) Wc[f / 9] = (__bf16)vv[j];
  }
}

// 512 blocks (2 per CU) = 256 N-tiles (8 img x 32 nb, BN=128) x 2 M-halves
// (BM=256). 512 threads = 8 waves; wave w owns M rows [mhalf*256+32w, +32).
// XCD-paired dispatch swizzle: xcd = bid&7, slot = bid>>3; slots (2t,2t+1) on
// one XCD are the two M-halves of the SAME N-tile -> the pair's shared fea
// panel dedups in that XCD's L2 (and in L3 on drift). A traffic stays 512 MB.
// 2 blocks/CU restores inter-block overlap across the per-iteration barrier
// drain (the R3 single-block structure exposed every vmcnt(0) stall).
// B: double-buffered LDS (128 hw x 32 k bf16, 2 x 8 KB), staged by all 8
// waves (hw = lane+64*(wave&1), g = wave>>1, k in [8g,8g+8)), depth-2
// register prefetch. Swizzle (4 granules of 8 bf16 per 64 B row):
// phys = (g + (hw>>1)) & 3 -> uniform 8 accesses/bank on ds_write_b128 AND
// ds_read_b128 (min possible; 2-way write aliasing of the naive layout gone).
__global__ __launch_bounds__(512, 4) void conv1x1_kernel(
    const float* __restrict__ fea, const __bf16* __restrict__ Wc,
    const float* __restrict__ bias, float* __restrict__ out) {
  __shared__ __align__(16) __bf16 Bs[2][BN * BK];   // 2 x 8 KB

  const int t    = threadIdx.x;
  const int wave = t >> 6;        // 0..7
  const int lane = t & 63;
  const int l15  = lane & 15;
  const int quad = lane >> 4;

  // XCD-paired decode
  const int xcd   = blockIdx.x & 7;
  const int slot  = blockIdx.x >> 3;          // 0..63
  const int tile  = xcd * 32 + (slot >> 1);   // 0..255
  const int mhalf = slot & 1;
  const int img   = tile >> 5;
  const int nb    = tile & 31;

  const int wm = mhalf * BM + wave * 32;      // M rows [wm, wm+32)

  const float* feaN = fea + (size_t)img * KDIM * HWDIM + (size_t)nb * BN;
  float*       outN = out + (size_t)img * MDIM * HWDIM + (size_t)nb * BN;

  // ---- B staging (all 8 waves): hw = lane+64*(wave&1), k in [8g, 8g+8) ----
  const int hw   = lane + ((wave & 1) << 6);             // 0..127
  const int g    = wave >> 1;                            // 0..3
  const int boff = hw * BK + (((g + (hw >> 1)) & 3) * 8);
  const float* bsrc = feaN + (size_t)g * 8 * HWDIM + hw;

  // ---- A: direct global loads from Wc (L2/L3-resident) ----
  const __bf16* aptr = Wc + (size_t)(wm + l15) * KDIM + quad * 8;

  float bpf[2][8];     // depth-2 B prefetch registers
  floatx4 acc[2][8];   // mt x nt
#pragma unroll
  for (int i = 0; i < 2; ++i)
#pragma unroll
    for (int j = 0; j < 8; ++j) acc[i][j] = (floatx4){0.f, 0.f, 0.f, 0.f};

  // ---- prologue: issue B(0), B(1); convert+write B(0) ----
#pragma unroll
  for (int j = 0; j < 8; ++j) bpf[0][j] = bsrc[(size_t)j * HWDIM];
#pragma unroll
  for (int j = 0; j < 8; ++j) bpf[1][j] = bsrc[(size_t)(BK + j) * HWDIM];
  {
    bf16x8 h0;
#pragma unroll
    for (int j = 0; j < 8; ++j) h0[j] = (__bf16)bpf[0][j];
    *(bf16x8*)&Bs[0][boff] = h0;
  }
  __syncthreads();

  // Body (CUR = i&1, compile-time):
  //  1) A-frag loads (L2/L3)
  //  2) convert+write B(i+1) to LDS
  //  3) issue B(i+2) prefetch
  //  4) ds_read B frags + MFMA
  //  5) __syncthreads (2 blocks/CU cover each other's drain)
#define KBODY(I, CUR)                                                          \
  {                                                                            \
    const int i_ = (I);                                                        \
    bf16x8 af[2];                                                              \
    const __bf16* ap = aptr + (size_t)i_ * BK;                                 \
    _Pragma("unroll")                                                          \
    for (int mt = 0; mt < 2; ++mt)                                             \
      af[mt] = *(const bf16x8*)(ap + (size_t)(mt * 16) * KDIM);                \
    if (i_ + 1 < NITER) {                                                      \
      bf16x8 hn;                                                               \
      _Pragma("unroll")                                                        \
      for (int j = 0; j < 8; ++j) hn[j] = (__bf16)bpf[(CUR) ^ 1][j];           \
      *(bf16x8*)&Bs[(CUR) ^ 1][boff] = hn;                                     \
    }                                                                          \
    if (i_ + 2 < NITER) {                                                      \
      const float* p = bsrc + (size_t)(i_ + 2) * BK * HWDIM;                   \
      _Pragma("unroll")                                                        \
      for (int j = 0; j < 8; ++j) bpf[(CUR)][j] = p[(size_t)j * HWDIM];        \
    }                                                                          \
    _Pragma("unroll")                                                          \
    for (int nt = 0; nt < 8; ++nt) {                                           \
      const int n_ = nt * 16 + l15;                                            \
      const bf16x8 bfr = *(const bf16x8*)&Bs[(CUR)][n_ * BK +                  \
                            (((quad + (n_ >> 1)) & 3) * 8)];                   \
      _Pragma("unroll")                                                        \
      for (int mt = 0; mt < 2; ++mt)                                           \
        acc[mt][nt] = __builtin_amdgcn_mfma_f32_16x16x32_bf16(af[mt], bfr,     \
                          acc[mt][nt], 0, 0, 0);                               \
    }                                                                          \
    __syncthreads();                                                           \
  }

  for (int i = 0; i < NITER; i += 2) {
    KBODY(i, 0)
    KBODY(i + 1, 1)
  }
#undef KBODY

  // Epilogue: bias + relu  (C/D: col = l15, row = quad*4 + r — verified)
#pragma unroll
  for (int mt = 0; mt < 2; ++mt) {
    const int o0 = wm + mt * 16 + quad * 4;
    const float4 bv = *(const float4*)(bias + o0);
    const float bvr[4] = {bv.x, bv.y, bv.z, bv.w};
#pragma unroll
    for (int r = 0; r < 4; ++r) {
      const size_t ro = (size_t)(o0 + r) * HWDIM;
#pragma unroll
      for (int nt = 0; nt < 8; ++nt) {
        float x = acc[mt][nt][r] + bvr[r];
        x = x > 0.f ? x : 0.f;
        __builtin_nontemporal_store(x, &outN[ro + nt * 16 + l15]);
      }
    }
  }
}

extern "C" void kernel_launch(void* const* d_in, const int* in_sizes, int n_in,
                              void* d_out, int out_size, void* d_ws, size_t ws_size,
                              hipStream_t stream) {
  const float* fea  = (const float*)d_in[0];
  const float* W    = (const float*)d_in[1];
  const float* bias = (const float*)d_in[2];
  float* out = (float*)d_out;
  __bf16* Wc = (__bf16*)d_ws;   // 2 MB scratch

  // 512*2048*9 floats / 4 per thread / 256 per block = 9216 blocks (exact)
  hipLaunchKernelGGL(extract_w_kernel, dim3(9216), dim3(256), 0, stream, W, Wc);
  hipLaunchKernelGGL(conv1x1_kernel, dim3(512), dim3(512), 0, stream, fea, Wc, bias, out);
}